// Round 2
// baseline (255.820 us; speedup 1.0000x reference)
//
#include <hip/hip_runtime.h>

#define TPB 256
#define NBLK 256          // blocks for edge-streaming kernels
#define BSH 8             // dst >> 8 -> bucket; 256 dsts per bucket
#define BCAP 6144         // LDS staging cap per bucket (mean 4092, +4sigma ~4350)

typedef __attribute__((ext_vector_type(4))) float f32x4;
typedef __attribute__((ext_vector_type(8))) short short8;

__device__ __forceinline__ unsigned short f2bf(float f) {
    unsigned u = __float_as_uint(f);
    u = (u + 0x7fffu + ((u >> 16) & 1u)) >> 16;
    return (unsigned short)u;
}
__device__ __forceinline__ float bflo(unsigned u) { return __uint_as_float(u << 16); }
__device__ __forceinline__ float bfhi(unsigned u) { return __uint_as_float(u & 0xffff0000u); }

// ============ pass A: per-block bucket histogram + W->bf16 (blocks 0..7) ========

__global__ __launch_bounds__(256) void k_bhist(const int* __restrict__ dst,
                                               int* __restrict__ blockhist,
                                               const float* __restrict__ W,
                                               unsigned short* __restrict__ wbf, int E) {
    __shared__ int sh[512];
    int t = threadIdx.x;
    sh[t] = 0; sh[t + 256] = 0;
    __syncthreads();
    int chunk = (E + NBLK - 1) / NBLK;
    int lo = blockIdx.x * chunk;
    int hi = min(E, lo + chunk);
    for (int e = lo + t; e < hi; e += 256)
        atomicAdd(&sh[dst[e] >> BSH], 1);          // LDS atomic only
    __syncthreads();
    int* row = blockhist + blockIdx.x * 512;
    row[t] = sh[t];
    row[t + 256] = sh[t + 256];

    // hoisted W -> bf16 conversion (independent of hist; used only by k_gemm)
    if (blockIdx.x < 8) {
        int gid = blockIdx.x * 256 + t;            // 0..2047, 8 floats each (128x128)
        const float* wp = W + gid * 8;
        float4 w0 = *(const float4*)wp;
        float4 w1 = *(const float4*)(wp + 4);
        union { unsigned short u[8]; uint4 q; } pk;
        pk.u[0] = f2bf(w0.x); pk.u[1] = f2bf(w0.y); pk.u[2] = f2bf(w0.z); pk.u[3] = f2bf(w0.w);
        pk.u[4] = f2bf(w1.x); pk.u[5] = f2bf(w1.y); pk.u[6] = f2bf(w1.z); pk.u[7] = f2bf(w1.w);
        *((uint4*)wbf + gid) = pk.q;
    }
}

// ============ pass B: per-bucket cross-block exclusive prefix (parallel) ========
// wave w owns bucket w; 128 blocks x 4 waves = 512 buckets. Replaces the old
// serial single-block 256-iteration matrix scan. Writes per-block exclusive
// offsets back into blockhist and the bucket total into ctot[w].

__global__ __launch_bounds__(256) void k_bpfx(int* __restrict__ blockhist,
                                              int* __restrict__ ctot) {
    const int wave = blockIdx.x * 4 + (threadIdx.x >> 6);
    const int lane = threadIdx.x & 63;
    int v[4];
    #pragma unroll
    for (int j = 0; j < 4; ++j) v[j] = blockhist[(lane * 4 + j) * 512 + wave];
    int s = v[0] + v[1] + v[2] + v[3];
    int incl = s;
    #pragma unroll
    for (int d = 1; d < 64; d <<= 1) {
        int o = __shfl_up(incl, d);
        if (lane >= d) incl += o;
    }
    int pre = incl - s;                            // exclusive over earlier blocks
    #pragma unroll
    for (int j = 0; j < 4; ++j) { blockhist[(lane * 4 + j) * 512 + wave] = pre; pre += v[j]; }
    if (lane == 63) ctot[wave] = incl;             // bucket total
}

// local helper: exclusive scan of ctot[512] into bb[513] (LDS), 256 threads.
// ~9 LDS rounds, sub-microsecond — cheaper than a dedicated launch.
__device__ __forceinline__ void bucket_base_scan(const int* __restrict__ ctot,
                                                 int (&tp)[2][256], int* bb,
                                                 int E, int t) {
    int v0 = ctot[2 * t], v1 = ctot[2 * t + 1];
    int p = v0 + v1;
    tp[0][t] = p;
    __syncthreads();
    int sb = 0;
    for (int d = 1; d < 256; d <<= 1) {
        int val = tp[sb][t] + ((t >= d) ? tp[sb][t - d] : 0);
        tp[sb ^ 1][t] = val;
        sb ^= 1;
        __syncthreads();
    }
    int base = tp[sb][t] - p;                      // exclusive pair base
    bb[2 * t] = base;
    bb[2 * t + 1] = base + v0;
    if (t == 0) bb[512] = E;
    __syncthreads();
}

// ============ pass C: scatter packed edges (no re-histogram, no global atomics) =
// packed[e] = (src << 8) | (dst & 255); bucket id implicit in position.

__global__ __launch_bounds__(256) void k_bscatter(const int* __restrict__ src,
                                                  const int* __restrict__ dst,
                                                  const int* __restrict__ blockhist,
                                                  const int* __restrict__ ctot,
                                                  unsigned* __restrict__ packed, int E) {
    __shared__ int tp[2][256];
    __shared__ int bb[513];
    __shared__ int cur[512];
    int t = threadIdx.x;
    bucket_base_scan(ctot, tp, bb, E, t);
    const int* row = blockhist + blockIdx.x * 512;
    cur[t]       = bb[t]       + row[t];
    cur[t + 256] = bb[t + 256] + row[t + 256];
    __syncthreads();
    int chunk = (E + NBLK - 1) / NBLK;
    int lo = blockIdx.x * chunk;
    int hi = min(E, lo + chunk);
    for (int e = lo + t; e < hi; e += 256) {
        int d = dst[e];
        int pos = atomicAdd(&cur[d >> BSH], 1);    // LDS atomic
        packed[pos] = ((unsigned)src[e] << 8) | (unsigned)(d & 255);
    }
}

// ============ pass D: per-bucket exact CSR + offsets + dinv ============
// sorted_src stores BYTE offsets of g-rows (src*256) so the aggregate gather
// needs no shift/mul in the address path. Fallback keeps correctness if a
// bucket ever exceeds BCAP.

__global__ __launch_bounds__(256) void k_bcsr(const unsigned* __restrict__ packed,
                                              const int* __restrict__ ctot,
                                              int* __restrict__ offsets,
                                              int* __restrict__ sorted_src,
                                              float* __restrict__ dinv, int N, int E, int NB) {
    __shared__ int tmp[2][256];
    __shared__ int bb[513];
    __shared__ int hist[256];
    __shared__ int scur[256];
    __shared__ unsigned stage[BCAP];
    int t = threadIdx.x;
    bucket_base_scan(ctot, tmp, bb, E, t);

    for (int b = blockIdx.x; b < NB; b += NBLK) {
        int s0 = bb[b], s1 = bb[b + 1];
        int cnt = s1 - s0;
        hist[t] = 0;
        __syncthreads();
        for (int e = s0 + t; e < s1; e += 256)
            atomicAdd(&hist[packed[e] & 255u], 1); // LDS atomic
        __syncthreads();
        int v = hist[t];
        tmp[0][t] = v;
        __syncthreads();
        int sb = 0;
        for (int d = 1; d < 256; d <<= 1) {
            int val = tmp[sb][t] + ((t >= d) ? tmp[sb][t - d] : 0);
            tmp[sb ^ 1][t] = val;
            sb ^= 1;
            __syncthreads();
        }
        int lbase = tmp[sb][t] - v;                // bucket-local exclusive base
        scur[t] = lbase;
        int d = (b << BSH) + t;
        if (d < N) { offsets[d] = s0 + lbase; dinv[d] = rsqrtf((float)v + 1.0f); }
        if (b == 0 && t == 0) offsets[N] = E;
        __syncthreads();
        if (cnt <= BCAP) {
            for (int e = s0 + t; e < s1; e += 256) {
                unsigned pk = packed[e];
                int pos = atomicAdd(&scur[pk & 255u], 1);  // LDS atomic
                stage[pos] = pk & 0xffffff00u;             // byte offset (src*256)
            }
            __syncthreads();
            for (int i = t; i < cnt; i += 256)
                sorted_src[s0 + i] = (int)stage[i];        // coalesced stream-out
        } else {
            for (int e = s0 + t; e < s1; e += 256) {
                unsigned pk = packed[e];
                int pos = atomicAdd(&scur[pk & 255u], 1);
                sorted_src[(long)s0 + pos] = (int)(pk & 0xffffff00u);
            }
        }
        __syncthreads();                           // before hist reuse next bucket
    }
}

// ============ GEMM via MFMA (swapped operands -> transposed D) ============
// g[i][j] = bf16( dinv[i] * sum_k x[i][k]*W[j][k] ).  W arrives pre-converted
// (wbf) so LDS staging is 8 plain uint4 copies/thread — no per-block f2bf of W.

__global__ __launch_bounds__(256) void k_gemm(const float* __restrict__ x,
                                              const unsigned short* __restrict__ wbf,
                                              const float* __restrict__ dinv,
                                              unsigned short* __restrict__ g, int n) {
    __shared__ unsigned short wb[128][136];
    const int tid = threadIdx.x;

    const uint4* wv = (const uint4*)wbf;
    for (int ch = tid; ch < 2048; ch += 256) {
        int nrow = ch >> 4, k8 = (ch & 15) << 3;
        *(uint4*)&wb[nrow][k8] = wv[ch];           // 8 bf16, 16B aligned
    }
    __syncthreads();

    const int lane = tid & 63;
    const int wid  = tid >> 6;
    const int l15  = lane & 15;
    const int quad = lane >> 4;
    const int row  = blockIdx.x * 64 + wid * 16 + l15;
    const int rowc = (row < n) ? row : (n - 1);

    f32x4 acc[8];
    #pragma unroll
    for (int t = 0; t < 8; ++t) acc[t] = (f32x4){0.f, 0.f, 0.f, 0.f};

    #pragma unroll
    for (int ks = 0; ks < 4; ++ks) {
        const int kb = ks * 32 + quad * 8;
        float4 a0 = *(const float4*)(x + (long)rowc * 128 + kb);
        float4 a1 = *(const float4*)(x + (long)rowc * 128 + kb + 4);
        union { unsigned short u[8]; short8 v; } af;
        af.u[0] = f2bf(a0.x); af.u[1] = f2bf(a0.y); af.u[2] = f2bf(a0.z); af.u[3] = f2bf(a0.w);
        af.u[4] = f2bf(a1.x); af.u[5] = f2bf(a1.y); af.u[6] = f2bf(a1.z); af.u[7] = f2bf(a1.w);
        #pragma unroll
        for (int t = 0; t < 8; ++t) {
            short8 bf = *(const short8*)&wb[t * 16 + l15][kb];
            // swapped: W frag as A, x frag as B  ->  D[j][i]
            acc[t] = __builtin_amdgcn_mfma_f32_16x16x32_bf16(bf, af.v, acc[t], 0, 0, 0);
        }
    }

    if (row < n) {
        float dv = dinv[row];
        unsigned short* gp = g + (long)row * 128 + quad * 4;
        #pragma unroll
        for (int t = 0; t < 8; ++t) {
            unsigned short u0 = f2bf(acc[t][0] * dv);
            unsigned short u1 = f2bf(acc[t][1] * dv);
            unsigned short u2 = f2bf(acc[t][2] * dv);
            unsigned short u3 = f2bf(acc[t][3] * dv);
            uint2 pk;
            pk.x = (unsigned)u0 | ((unsigned)u1 << 16);
            pk.y = (unsigned)u2 | ((unsigned)u3 << 16);
            *(uint2*)(gp + t * 16) = pk;           // 4 consecutive bf16 cols
        }
    }
}

// ============ CSR aggregate: out[d] = dinv[d]*(g[d] + sum g[src]) + b ============
// 16 lanes per dst, uint4 (16B) gathers: same bytes as the 32-lane/8B version but
// half the load+address instructions and 2x in-flight bytes per lane.
// sorted_src holds byte offsets (src*256) — no mul/shift in the gather address.

__global__ __launch_bounds__(256) void k_aggregate(const int* __restrict__ sorted_src,
                                                   const int* __restrict__ offsets,
                                                   const unsigned short* __restrict__ g,
                                                   const float* __restrict__ dinv,
                                                   const float* __restrict__ b,
                                                   float* __restrict__ out, int n) {
    int d = blockIdx.x * (TPB / 16) + (threadIdx.x >> 4);
    if (d >= n) return;
    int c = (threadIdx.x & 15) << 3;               // 8 float columns per lane
    const char* gb = (const char*)g + (c << 1);    // 16B lane base inside a g-row

    int s0 = offsets[d];
    int s1 = offsets[d + 1];

    float acc[8];
    #pragma unroll
    for (int j = 0; j < 8; ++j) acc[j] = 0.f;
    auto addrow = [&](int off) {                   // off = byte offset of g-row
        uint4 p = *(const uint4*)(gb + off);
        acc[0] += bflo(p.x); acc[1] += bfhi(p.x);
        acc[2] += bflo(p.y); acc[3] += bfhi(p.y);
        acc[4] += bflo(p.z); acc[5] += bfhi(p.z);
        acc[6] += bflo(p.w); acc[7] += bfhi(p.w);
    };

    addrow(d << 8);  // self-loop (d*256 bytes)
    int e = s0;
    for (; e + 16 <= s1; e += 16) {
        int a[16];
        #pragma unroll
        for (int j = 0; j < 16; ++j) a[j] = sorted_src[e + j];
        #pragma unroll
        for (int j = 0; j < 16; ++j) addrow(a[j]);
    }
    for (; e + 8 <= s1; e += 8) {
        int a[8];
        #pragma unroll
        for (int j = 0; j < 8; ++j) a[j] = sorted_src[e + j];
        #pragma unroll
        for (int j = 0; j < 8; ++j) addrow(a[j]);
    }
    for (; e + 4 <= s1; e += 4) {
        int a[4];
        #pragma unroll
        for (int j = 0; j < 4; ++j) a[j] = sorted_src[e + j];
        #pragma unroll
        for (int j = 0; j < 4; ++j) addrow(a[j]);
    }
    for (; e < s1; ++e) addrow(sorted_src[e]);

    float s = dinv[d];
    float4 b0 = *(const float4*)(b + c);
    float4 b1 = *(const float4*)(b + c + 4);
    float* op = out + (long)d * 128 + c;
    float4 r0 = make_float4(acc[0] * s + b0.x, acc[1] * s + b0.y,
                            acc[2] * s + b0.z, acc[3] * s + b0.w);
    float4 r1 = make_float4(acc[4] * s + b1.x, acc[5] * s + b1.y,
                            acc[6] * s + b1.z, acc[7] * s + b1.w);
    *(float4*)op = r0;
    *(float4*)(op + 4) = r1;
}

// ============ launch ============

extern "C" void kernel_launch(void* const* d_in, const int* in_sizes, int n_in,
                              void* d_out, int out_size, void* d_ws, size_t ws_size,
                              hipStream_t stream) {
    const float* x  = (const float*)d_in[0];
    const int*   ei = (const int*)d_in[1];
    // d_in[2] = edge_attr (unused; GCN edge weight = 1)
    const float* W  = (const float*)d_in[3];
    const float* b  = (const float*)d_in[4];
    float* out = (float*)d_out;

    const int N = in_sizes[0] / 128;
    const int E = in_sizes[1] / 2;
    const int* src = ei;
    const int* dst = ei + E;
    const int NB = (N + 255) >> BSH;   // 391 buckets (<= 512)

    // ---- workspace carve (~40 MB) ----
    char* p = (char*)d_ws;
    auto carve = [&](size_t bytes) { char* q = p; p += (bytes + 255) & ~(size_t)255; return q; };
    int*            blockhist  = (int*)           carve((size_t)NBLK * 512 * 4);
    int*            ctot       = (int*)           carve(512 * 4);
    int*            offsets    = (int*)           carve((size_t)(N + 1) * 4);
    float*          dinv       = (float*)         carve((size_t)N * 4);
    unsigned*       packed     = (unsigned*)      carve((size_t)E * 4);
    int*            sorted_src = (int*)           carve((size_t)E * 4);
    unsigned short* wbf        = (unsigned short*)carve((size_t)128 * 128 * 2);
    unsigned short* g          = (unsigned short*)carve((size_t)N * 128 * 2);

    k_bhist   <<<NBLK, TPB, 0, stream>>>(dst, blockhist, W, wbf, E);
    k_bpfx    <<<128, TPB, 0, stream>>>(blockhist, ctot);
    k_bscatter<<<NBLK, TPB, 0, stream>>>(src, dst, blockhist, ctot, packed, E);
    k_bcsr    <<<NB, TPB, 0, stream>>>(packed, ctot, offsets, sorted_src, dinv, N, E, NB);

    k_gemm<<<(N + 63) / 64, TPB, 0, stream>>>(x, wbf, dinv, g, N);

    k_aggregate<<<(N + (TPB / 16) - 1) / (TPB / 16), TPB, 0, stream>>>(
        sorted_src, offsets, g, dinv, b, out, N);
}

// Round 4
// 247.255 us; speedup vs baseline: 1.0346x; 1.0346x over previous
//
#include <hip/hip_runtime.h>

#define TPB 256
#define NBLK 256          // blocks for edge-streaming kernels
#define BSH 8             // dst >> 8 -> bucket; 256 dsts per bucket
#define BCAP 6144         // LDS staging cap per bucket (mean 4092, +4sigma ~4350)

typedef __attribute__((ext_vector_type(4))) float f32x4;
typedef __attribute__((ext_vector_type(8))) short short8;

__device__ __forceinline__ unsigned short f2bf(float f) {
    unsigned u = __float_as_uint(f);
    u = (u + 0x7fffu + ((u >> 16) & 1u)) >> 16;
    return (unsigned short)u;
}
__device__ __forceinline__ float bflo(unsigned u) { return __uint_as_float(u << 16); }
__device__ __forceinline__ float bfhi(unsigned u) { return __uint_as_float(u & 0xffff0000u); }

// ============ pass A: per-block bucket histogram + W->bf16 (blocks 0..7) ========

__global__ __launch_bounds__(256) void k_bhist(const int* __restrict__ dst,
                                               int* __restrict__ blockhist,
                                               const float* __restrict__ W,
                                               unsigned short* __restrict__ wbf, int E) {
    __shared__ int sh[512];
    int t = threadIdx.x;
    sh[t] = 0; sh[t + 256] = 0;
    __syncthreads();
    int chunk = (E + NBLK - 1) / NBLK;
    int lo = blockIdx.x * chunk;
    int hi = min(E, lo + chunk);
    for (int e = lo + t; e < hi; e += 256)
        atomicAdd(&sh[dst[e] >> BSH], 1);          // LDS atomic only
    __syncthreads();
    int* row = blockhist + blockIdx.x * 512;
    row[t] = sh[t];
    row[t + 256] = sh[t + 256];

    // hoisted W -> bf16 conversion (independent of hist; used only by k_gemm)
    if (blockIdx.x < 8) {
        int gid = blockIdx.x * 256 + t;            // 0..2047, 8 floats each (128x128)
        const float* wp = W + gid * 8;
        float4 w0 = *(const float4*)wp;
        float4 w1 = *(const float4*)(wp + 4);
        union { unsigned short u[8]; uint4 q; } pk;
        pk.u[0] = f2bf(w0.x); pk.u[1] = f2bf(w0.y); pk.u[2] = f2bf(w0.z); pk.u[3] = f2bf(w0.w);
        pk.u[4] = f2bf(w1.x); pk.u[5] = f2bf(w1.y); pk.u[6] = f2bf(w1.z); pk.u[7] = f2bf(w1.w);
        *((uint4*)wbf + gid) = pk.q;
    }
}

// ============ pass B: per-bucket cross-block exclusive prefix (parallel) ========
// wave w owns bucket w; 128 blocks x 4 waves = 512 buckets.

__global__ __launch_bounds__(256) void k_bpfx(int* __restrict__ blockhist,
                                              int* __restrict__ ctot) {
    const int wave = blockIdx.x * 4 + (threadIdx.x >> 6);
    const int lane = threadIdx.x & 63;
    int v[4];
    #pragma unroll
    for (int j = 0; j < 4; ++j) v[j] = blockhist[(lane * 4 + j) * 512 + wave];
    int s = v[0] + v[1] + v[2] + v[3];
    int incl = s;
    #pragma unroll
    for (int d = 1; d < 64; d <<= 1) {
        int o = __shfl_up(incl, d);
        if (lane >= d) incl += o;
    }
    int pre = incl - s;                            // exclusive over earlier blocks
    #pragma unroll
    for (int j = 0; j < 4; ++j) { blockhist[(lane * 4 + j) * 512 + wave] = pre; pre += v[j]; }
    if (lane == 63) ctot[wave] = incl;             // bucket total
}

// local helper: exclusive scan of ctot[512] into bb[513] (LDS), 256 threads.
__device__ __forceinline__ void bucket_base_scan(const int* __restrict__ ctot,
                                                 int (&tp)[2][256], int* bb,
                                                 int E, int t) {
    int v0 = ctot[2 * t], v1 = ctot[2 * t + 1];
    int p = v0 + v1;
    tp[0][t] = p;
    __syncthreads();
    int sb = 0;
    for (int d = 1; d < 256; d <<= 1) {
        int val = tp[sb][t] + ((t >= d) ? tp[sb][t - d] : 0);
        tp[sb ^ 1][t] = val;
        sb ^= 1;
        __syncthreads();
    }
    int base = tp[sb][t] - p;                      // exclusive pair base
    bb[2 * t] = base;
    bb[2 * t + 1] = base + v0;
    if (t == 0) bb[512] = E;
    __syncthreads();
}

// ============ pass C: scatter packed edges (no re-histogram, no global atomics) =

__global__ __launch_bounds__(256) void k_bscatter(const int* __restrict__ src,
                                                  const int* __restrict__ dst,
                                                  const int* __restrict__ blockhist,
                                                  const int* __restrict__ ctot,
                                                  unsigned* __restrict__ packed, int E) {
    __shared__ int tp[2][256];
    __shared__ int bb[513];
    __shared__ int cur[512];
    int t = threadIdx.x;
    bucket_base_scan(ctot, tp, bb, E, t);
    const int* row = blockhist + blockIdx.x * 512;
    cur[t]       = bb[t]       + row[t];
    cur[t + 256] = bb[t + 256] + row[t + 256];
    __syncthreads();
    int chunk = (E + NBLK - 1) / NBLK;
    int lo = blockIdx.x * chunk;
    int hi = min(E, lo + chunk);
    for (int e = lo + t; e < hi; e += 256) {
        int d = dst[e];
        int pos = atomicAdd(&cur[d >> BSH], 1);    // LDS atomic
        packed[pos] = ((unsigned)src[e] << 8) | (unsigned)(d & 255);
    }
}

// ============ pass D: per-bucket exact CSR + offsets + dinv ============
// sorted_src stores BYTE offsets of g-rows (src*256).

__global__ __launch_bounds__(256) void k_bcsr(const unsigned* __restrict__ packed,
                                              const int* __restrict__ ctot,
                                              int* __restrict__ offsets,
                                              int* __restrict__ sorted_src,
                                              float* __restrict__ dinv, int N, int E, int NB) {
    __shared__ int tmp[2][256];
    __shared__ int bb[513];
    __shared__ int hist[256];
    __shared__ int scur[256];
    __shared__ unsigned stage[BCAP];
    int t = threadIdx.x;
    bucket_base_scan(ctot, tmp, bb, E, t);

    for (int b = blockIdx.x; b < NB; b += NBLK) {
        int s0 = bb[b], s1 = bb[b + 1];
        int cnt = s1 - s0;
        hist[t] = 0;
        __syncthreads();
        for (int e = s0 + t; e < s1; e += 256)
            atomicAdd(&hist[packed[e] & 255u], 1); // LDS atomic
        __syncthreads();
        int v = hist[t];
        tmp[0][t] = v;
        __syncthreads();
        int sb = 0;
        for (int d = 1; d < 256; d <<= 1) {
            int val = tmp[sb][t] + ((t >= d) ? tmp[sb][t - d] : 0);
            tmp[sb ^ 1][t] = val;
            sb ^= 1;
            __syncthreads();
        }
        int lbase = tmp[sb][t] - v;                // bucket-local exclusive base
        scur[t] = lbase;
        int d = (b << BSH) + t;
        if (d < N) { offsets[d] = s0 + lbase; dinv[d] = rsqrtf((float)v + 1.0f); }
        if (b == 0 && t == 0) offsets[N] = E;
        __syncthreads();
        if (cnt <= BCAP) {
            for (int e = s0 + t; e < s1; e += 256) {
                unsigned pk = packed[e];
                int pos = atomicAdd(&scur[pk & 255u], 1);  // LDS atomic
                stage[pos] = pk & 0xffffff00u;             // byte offset (src*256)
            }
            __syncthreads();
            for (int i = t; i < cnt; i += 256)
                sorted_src[s0 + i] = (int)stage[i];        // coalesced stream-out
        } else {
            for (int e = s0 + t; e < s1; e += 256) {
                unsigned pk = packed[e];
                int pos = atomicAdd(&scur[pk & 255u], 1);
                sorted_src[(long)s0 + pos] = (int)(pk & 0xffffff00u);
            }
        }
        __syncthreads();                           // before hist reuse next bucket
    }
}

// ============ GEMM via MFMA (swapped operands -> transposed D) ============
// x loaded nontemporal (read-once 51 MB) so it doesn't evict g from L2/L3.
// NOTE: nontemporal builtins need native ext-vector types, not HIP float4.

__global__ __launch_bounds__(256) void k_gemm(const float* __restrict__ x,
                                              const unsigned short* __restrict__ wbf,
                                              const float* __restrict__ dinv,
                                              unsigned short* __restrict__ g, int n) {
    __shared__ unsigned short wb[128][136];
    const int tid = threadIdx.x;

    const uint4* wv = (const uint4*)wbf;
    for (int ch = tid; ch < 2048; ch += 256) {
        int nrow = ch >> 4, k8 = (ch & 15) << 3;
        *(uint4*)&wb[nrow][k8] = wv[ch];           // 8 bf16, 16B aligned
    }
    __syncthreads();

    const int lane = tid & 63;
    const int wid  = tid >> 6;
    const int l15  = lane & 15;
    const int quad = lane >> 4;
    const int row  = blockIdx.x * 64 + wid * 16 + l15;
    const int rowc = (row < n) ? row : (n - 1);

    f32x4 acc[8];
    #pragma unroll
    for (int t = 0; t < 8; ++t) acc[t] = (f32x4){0.f, 0.f, 0.f, 0.f};

    #pragma unroll
    for (int ks = 0; ks < 4; ++ks) {
        const int kb = ks * 32 + quad * 8;
        const f32x4* xp = (const f32x4*)(x + (long)rowc * 128 + kb);
        f32x4 a0 = __builtin_nontemporal_load(xp);
        f32x4 a1 = __builtin_nontemporal_load(xp + 1);
        union { unsigned short u[8]; short8 v; } af;
        af.u[0] = f2bf(a0.x); af.u[1] = f2bf(a0.y); af.u[2] = f2bf(a0.z); af.u[3] = f2bf(a0.w);
        af.u[4] = f2bf(a1.x); af.u[5] = f2bf(a1.y); af.u[6] = f2bf(a1.z); af.u[7] = f2bf(a1.w);
        #pragma unroll
        for (int t = 0; t < 8; ++t) {
            short8 bf = *(const short8*)&wb[t * 16 + l15][kb];
            // swapped: W frag as A, x frag as B  ->  D[j][i]
            acc[t] = __builtin_amdgcn_mfma_f32_16x16x32_bf16(bf, af.v, acc[t], 0, 0, 0);
        }
    }

    if (row < n) {
        float dv = dinv[row];
        unsigned short* gp = g + (long)row * 128 + quad * 4;
        #pragma unroll
        for (int t = 0; t < 8; ++t) {
            unsigned short u0 = f2bf(acc[t][0] * dv);
            unsigned short u1 = f2bf(acc[t][1] * dv);
            unsigned short u2 = f2bf(acc[t][2] * dv);
            unsigned short u3 = f2bf(acc[t][3] * dv);
            uint2 pk;
            pk.x = (unsigned)u0 | ((unsigned)u1 << 16);
            pk.y = (unsigned)u2 | ((unsigned)u3 << 16);
            *(uint2*)(gp + t * 16) = pk;           // 4 consecutive bf16 cols; keep cached
        }
    }
}

// ============ CSR aggregate: out[d] = dinv[d]*(g[d] + sum g[src]) + b ============
// R0-proven config: 32 lanes per dst, uint2 gathers, 8/4/1 ladder (VGPR ~24,
// ~70% occupancy — gather-latency-bound, needs the TLP).
// sorted_src holds byte offsets (src*256): no mul/shift in the gather address.
// sorted_src loads + out stores are nontemporal so the read-once/write-once
// streams don't evict the 25.6 MB g table from L2/L3.

__global__ __launch_bounds__(256) void k_aggregate(const int* __restrict__ sorted_src,
                                                   const int* __restrict__ offsets,
                                                   const unsigned short* __restrict__ g,
                                                   const float* __restrict__ dinv,
                                                   const float* __restrict__ b,
                                                   float* __restrict__ out, int n) {
    int d = blockIdx.x * (TPB / 32) + (threadIdx.x >> 5);
    if (d >= n) return;
    int c = (threadIdx.x & 31) << 2;
    const char* gb = (const char*)g + (c << 1);   // lane base inside a g-row

    int s0 = offsets[d];
    int s1 = offsets[d + 1];

    float4 acc = make_float4(0.f, 0.f, 0.f, 0.f);
    auto addrow = [&](int off) {                  // off = byte offset of g-row
        uint2 p = *(const uint2*)(gb + off);
        acc.x += bflo(p.x); acc.y += bfhi(p.x);
        acc.z += bflo(p.y); acc.w += bfhi(p.y);
    };

    addrow(d << 8);  // self-loop (d*256 bytes)
    int e = s0;
    for (; e + 8 <= s1; e += 8) {
        int a[8];
        #pragma unroll
        for (int j = 0; j < 8; ++j) a[j] = __builtin_nontemporal_load(&sorted_src[e + j]);
        #pragma unroll
        for (int j = 0; j < 8; ++j) addrow(a[j]);
    }
    for (; e + 4 <= s1; e += 4) {
        int a[4];
        #pragma unroll
        for (int j = 0; j < 4; ++j) a[j] = __builtin_nontemporal_load(&sorted_src[e + j]);
        #pragma unroll
        for (int j = 0; j < 4; ++j) addrow(a[j]);
    }
    for (; e < s1; ++e) addrow(__builtin_nontemporal_load(&sorted_src[e]));

    float s = dinv[d];
    float4 bb = *(const float4*)(b + c);
    f32x4 r = (f32x4){acc.x * s + bb.x, acc.y * s + bb.y,
                      acc.z * s + bb.z, acc.w * s + bb.w};
    __builtin_nontemporal_store(r, (f32x4*)(out + (long)d * 128 + c));
}

// ============ launch ============

extern "C" void kernel_launch(void* const* d_in, const int* in_sizes, int n_in,
                              void* d_out, int out_size, void* d_ws, size_t ws_size,
                              hipStream_t stream) {
    const float* x  = (const float*)d_in[0];
    const int*   ei = (const int*)d_in[1];
    // d_in[2] = edge_attr (unused; GCN edge weight = 1)
    const float* W  = (const float*)d_in[3];
    const float* b  = (const float*)d_in[4];
    float* out = (float*)d_out;

    const int N = in_sizes[0] / 128;
    const int E = in_sizes[1] / 2;
    const int* src = ei;
    const int* dst = ei + E;
    const int NB = (N + 255) >> BSH;   // 391 buckets (<= 512)

    // ---- workspace carve (~40 MB) ----
    char* p = (char*)d_ws;
    auto carve = [&](size_t bytes) { char* q = p; p += (bytes + 255) & ~(size_t)255; return q; };
    int*            blockhist  = (int*)           carve((size_t)NBLK * 512 * 4);
    int*            ctot       = (int*)           carve(512 * 4);
    int*            offsets    = (int*)           carve((size_t)(N + 1) * 4);
    float*          dinv       = (float*)         carve((size_t)N * 4);
    unsigned*       packed     = (unsigned*)      carve((size_t)E * 4);
    int*            sorted_src = (int*)           carve((size_t)E * 4);
    unsigned short* wbf        = (unsigned short*)carve((size_t)128 * 128 * 2);
    unsigned short* g          = (unsigned short*)carve((size_t)N * 128 * 2);

    k_bhist   <<<NBLK, TPB, 0, stream>>>(dst, blockhist, W, wbf, E);
    k_bpfx    <<<128, TPB, 0, stream>>>(blockhist, ctot);
    k_bscatter<<<NBLK, TPB, 0, stream>>>(src, dst, blockhist, ctot, packed, E);
    k_bcsr    <<<NB, TPB, 0, stream>>>(packed, ctot, offsets, sorted_src, dinv, N, E, NB);

    k_gemm<<<(N + 63) / 64, TPB, 0, stream>>>(x, wbf, dinv, g, N);

    k_aggregate<<<(N + (TPB / 32) - 1) / (TPB / 32), TPB, 0, stream>>>(
        sorted_src, offsets, g, dinv, b, out, N);
}

// Round 5
// 238.698 us; speedup vs baseline: 1.0717x; 1.0358x over previous
//
#include <hip/hip_runtime.h>

#define TPB 256
#define NBLK 256          // blocks for edge-streaming kernels / bcsr half of fused kernel
#define BSH 8             // dst >> 8 -> bucket; 256 dsts per bucket
#define BCAP 6144         // LDS staging cap per bucket (mean 4092, +4sigma ~4350)

typedef __attribute__((ext_vector_type(4))) float f32x4;
typedef __attribute__((ext_vector_type(8))) short short8;

__device__ __forceinline__ unsigned short f2bf(float f) {
    unsigned u = __float_as_uint(f);
    u = (u + 0x7fffu + ((u >> 16) & 1u)) >> 16;
    return (unsigned short)u;
}
__device__ __forceinline__ float bflo(unsigned u) { return __uint_as_float(u << 16); }
__device__ __forceinline__ float bfhi(unsigned u) { return __uint_as_float(u & 0xffff0000u); }

// ============ pass A: per-block bucket histogram + W->bf16 (blocks 0..7) ========

__global__ __launch_bounds__(256) void k_bhist(const int* __restrict__ dst,
                                               int* __restrict__ blockhist,
                                               const float* __restrict__ W,
                                               unsigned short* __restrict__ wbf, int E) {
    __shared__ int sh[512];
    int t = threadIdx.x;
    sh[t] = 0; sh[t + 256] = 0;
    __syncthreads();
    int chunk = (E + NBLK - 1) / NBLK;
    int lo = blockIdx.x * chunk;
    int hi = min(E, lo + chunk);
    for (int e = lo + t; e < hi; e += 256)
        atomicAdd(&sh[dst[e] >> BSH], 1);          // LDS atomic only
    __syncthreads();
    int* row = blockhist + blockIdx.x * 512;
    row[t] = sh[t];
    row[t + 256] = sh[t + 256];

    // hoisted W -> bf16 conversion (independent of hist; used only by gemm)
    if (blockIdx.x < 8) {
        int gid = blockIdx.x * 256 + t;            // 0..2047, 8 floats each (128x128)
        const float* wp = W + gid * 8;
        float4 w0 = *(const float4*)wp;
        float4 w1 = *(const float4*)(wp + 4);
        union { unsigned short u[8]; uint4 q; } pk;
        pk.u[0] = f2bf(w0.x); pk.u[1] = f2bf(w0.y); pk.u[2] = f2bf(w0.z); pk.u[3] = f2bf(w0.w);
        pk.u[4] = f2bf(w1.x); pk.u[5] = f2bf(w1.y); pk.u[6] = f2bf(w1.z); pk.u[7] = f2bf(w1.w);
        *((uint4*)wbf + gid) = pk.q;
    }
}

// ============ pass B: per-bucket cross-block exclusive prefix (parallel) ========
// wave w owns bucket w; 128 blocks x 4 waves = 512 buckets.

__global__ __launch_bounds__(256) void k_bpfx(int* __restrict__ blockhist,
                                              int* __restrict__ ctot) {
    const int wave = blockIdx.x * 4 + (threadIdx.x >> 6);
    const int lane = threadIdx.x & 63;
    int v[4];
    #pragma unroll
    for (int j = 0; j < 4; ++j) v[j] = blockhist[(lane * 4 + j) * 512 + wave];
    int s = v[0] + v[1] + v[2] + v[3];
    int incl = s;
    #pragma unroll
    for (int d = 1; d < 64; d <<= 1) {
        int o = __shfl_up(incl, d);
        if (lane >= d) incl += o;
    }
    int pre = incl - s;                            // exclusive over earlier blocks
    #pragma unroll
    for (int j = 0; j < 4; ++j) { blockhist[(lane * 4 + j) * 512 + wave] = pre; pre += v[j]; }
    if (lane == 63) ctot[wave] = incl;             // bucket total
}

// local helper: exclusive scan of ctot[512] into bb[513] (LDS), 256 threads.
__device__ __forceinline__ void bucket_base_scan(const int* __restrict__ ctot,
                                                 int* tp0, int* tp1, int* bb,
                                                 int E, int t) {
    int v0 = ctot[2 * t], v1 = ctot[2 * t + 1];
    int p = v0 + v1;
    tp0[t] = p;
    __syncthreads();
    int sb = 0;
    for (int d = 1; d < 256; d <<= 1) {
        int* cur = sb ? tp1 : tp0;
        int* nxt = sb ? tp0 : tp1;
        int val = cur[t] + ((t >= d) ? cur[t - d] : 0);
        nxt[t] = val;
        sb ^= 1;
        __syncthreads();
    }
    int* fin = sb ? tp1 : tp0;
    int base = fin[t] - p;                         // exclusive pair base
    bb[2 * t] = base;
    bb[2 * t + 1] = base + v0;
    if (t == 0) bb[512] = E;
    __syncthreads();
}

// ============ pass C: scatter packed edges (no re-histogram, no global atomics) =

__global__ __launch_bounds__(256) void k_bscatter(const int* __restrict__ src,
                                                  const int* __restrict__ dst,
                                                  const int* __restrict__ blockhist,
                                                  const int* __restrict__ ctot,
                                                  unsigned* __restrict__ packed, int E) {
    __shared__ int tp0[256], tp1[256];
    __shared__ int bb[513];
    __shared__ int cur[512];
    int t = threadIdx.x;
    bucket_base_scan(ctot, tp0, tp1, bb, E, t);
    const int* row = blockhist + blockIdx.x * 512;
    cur[t]       = bb[t]       + row[t];
    cur[t + 256] = bb[t + 256] + row[t + 256];
    __syncthreads();
    int chunk = (E + NBLK - 1) / NBLK;
    int lo = blockIdx.x * chunk;
    int hi = min(E, lo + chunk);
    for (int e = lo + t; e < hi; e += 256) {
        int d = dst[e];
        int pos = atomicAdd(&cur[d >> BSH], 1);    // LDS atomic
        packed[pos] = ((unsigned)src[e] << 8) | (unsigned)(d & 255);
    }
}

// ============ fused pass D: bcsr (blocks 0..NBLK-1)  ||  gemm (blocks NBLK..) ====
// bcsr: per-bucket exact CSR + offsets + dinv; sorted_src stores plain src index.
// gemm: g[i][j] = bf16( sum_k x[i][k]*W[j][k] )  -- NO dinv (applied in aggregate),
//       which breaks the gemm->dinv dependency and lets both halves share 1 launch.
// 35 KB aliased LDS: bcsr needs ~30.7 KB, gemm wb[128][136] = 34.8 KB.

__global__ __launch_bounds__(256) void k_csrgemm(
    const unsigned* __restrict__ packed, const int* __restrict__ ctot,
    int* __restrict__ offsets, int* __restrict__ sorted_src, float* __restrict__ dinv,
    const float* __restrict__ x, const unsigned short* __restrict__ wbf,
    unsigned short* __restrict__ g, int N, int E, int NB)
{
    __shared__ __align__(16) char smem[34816];
    const int t = threadIdx.x;

    if (blockIdx.x < NBLK) {
        // ---------------- bcsr half ----------------
        int* tp0  = (int*)smem;                    // 1024 B
        int* tp1  = tp0 + 256;                     // 1024 B
        int* bb   = tp1 + 256;                     // 2052 B
        int* hist = bb + 516;                      // 1024 B (513 rounded to 516)
        int* scur = hist + 256;                    // 1024 B
        unsigned* stage = (unsigned*)(scur + 256); // 24576 B  -> total 30724 B
        bucket_base_scan(ctot, tp0, tp1, bb, E, t);

        for (int b = blockIdx.x; b < NB; b += NBLK) {
            int s0 = bb[b], s1 = bb[b + 1];
            int cnt = s1 - s0;
            hist[t] = 0;
            __syncthreads();
            for (int e = s0 + t; e < s1; e += 256)
                atomicAdd(&hist[packed[e] & 255u], 1);   // LDS atomic
            __syncthreads();
            int v = hist[t];
            tp0[t] = v;
            __syncthreads();
            int sb = 0;
            for (int d = 1; d < 256; d <<= 1) {
                int* cur = sb ? tp1 : tp0;
                int* nxt = sb ? tp0 : tp1;
                int val = cur[t] + ((t >= d) ? cur[t - d] : 0);
                nxt[t] = val;
                sb ^= 1;
                __syncthreads();
            }
            int* fin = sb ? tp1 : tp0;
            int lbase = fin[t] - v;                // bucket-local exclusive base
            scur[t] = lbase;
            int d = (b << BSH) + t;
            if (d < N) { offsets[d] = s0 + lbase; dinv[d] = rsqrtf((float)v + 1.0f); }
            if (b == 0 && t == 0) offsets[N] = E;
            __syncthreads();
            if (cnt <= BCAP) {
                for (int e = s0 + t; e < s1; e += 256) {
                    unsigned pk = packed[e];
                    int pos = atomicAdd(&scur[pk & 255u], 1);  // LDS atomic
                    stage[pos] = pk >> 8;                      // plain src index
                }
                __syncthreads();
                for (int i = t; i < cnt; i += 256)
                    sorted_src[s0 + i] = (int)stage[i];        // coalesced stream-out
            } else {
                for (int e = s0 + t; e < s1; e += 256) {
                    unsigned pk = packed[e];
                    int pos = atomicAdd(&scur[pk & 255u], 1);
                    sorted_src[(long)s0 + pos] = (int)(pk >> 8);
                }
            }
            __syncthreads();                       // before hist reuse next bucket
        }
    } else {
        // ---------------- gemm half ----------------
        typedef unsigned short wb_t[136];
        wb_t* wb = (wb_t*)smem;                    // [128][136] bf16 = 34816 B

        const uint4* wv = (const uint4*)wbf;
        for (int ch = t; ch < 2048; ch += 256) {
            int nrow = ch >> 4, k8 = (ch & 15) << 3;
            *(uint4*)&wb[nrow][k8] = wv[ch];       // 8 bf16, 16B aligned
        }
        __syncthreads();

        const int lane = t & 63;
        const int wid  = t >> 6;
        const int l15  = lane & 15;
        const int quad = lane >> 4;
        const int row  = (blockIdx.x - NBLK) * 64 + wid * 16 + l15;
        const int rowc = (row < N) ? row : (N - 1);

        f32x4 acc[8];
        #pragma unroll
        for (int u = 0; u < 8; ++u) acc[u] = (f32x4){0.f, 0.f, 0.f, 0.f};

        #pragma unroll
        for (int ks = 0; ks < 4; ++ks) {
            const int kb = ks * 32 + quad * 8;
            float4 a0 = *(const float4*)(x + (long)rowc * 128 + kb);
            float4 a1 = *(const float4*)(x + (long)rowc * 128 + kb + 4);
            union { unsigned short u[8]; short8 v; } af;
            af.u[0] = f2bf(a0.x); af.u[1] = f2bf(a0.y); af.u[2] = f2bf(a0.z); af.u[3] = f2bf(a0.w);
            af.u[4] = f2bf(a1.x); af.u[5] = f2bf(a1.y); af.u[6] = f2bf(a1.z); af.u[7] = f2bf(a1.w);
            #pragma unroll
            for (int u = 0; u < 8; ++u) {
                short8 bf = *(const short8*)&wb[u * 16 + l15][kb];
                // swapped: W frag as A, x frag as B  ->  D[j][i]
                acc[u] = __builtin_amdgcn_mfma_f32_16x16x32_bf16(bf, af.v, acc[u], 0, 0, 0);
            }
        }

        if (row < N) {
            unsigned short* gp = g + (long)row * 128 + quad * 4;
            #pragma unroll
            for (int u = 0; u < 8; ++u) {
                unsigned short u0 = f2bf(acc[u][0]);
                unsigned short u1 = f2bf(acc[u][1]);
                unsigned short u2 = f2bf(acc[u][2]);
                unsigned short u3 = f2bf(acc[u][3]);
                uint2 pk;
                pk.x = (unsigned)u0 | ((unsigned)u1 << 16);
                pk.y = (unsigned)u2 | ((unsigned)u3 << 16);
                *(uint2*)(gp + u * 16) = pk;       // 4 consecutive bf16 cols
            }
        }
    }
}

// ============ CSR aggregate: out[d] = dinv[d]*(Σ dinv[s]*g[s] + dinv[d]*g[d]) + b =
// R0-proven latency-hiding shape: 32 lanes per dst, uint2 gathers, 8/4/1 ladder,
// plain (cached) loads/stores. dinv[s] is a per-edge broadcast load from an
// L2-resident 400 KB table; the per-element add becomes an fma (same VALU count).

__global__ __launch_bounds__(256) void k_aggregate(const int* __restrict__ sorted_src,
                                                   const int* __restrict__ offsets,
                                                   const unsigned short* __restrict__ g,
                                                   const float* __restrict__ dinv,
                                                   const float* __restrict__ b,
                                                   float* __restrict__ out, int n) {
    int d = blockIdx.x * (TPB / 32) + (threadIdx.x >> 5);
    if (d >= n) return;
    int c = (threadIdx.x & 31) << 2;
    const char* gb = (const char*)g + (c << 1);   // lane base inside a g-row

    int s0 = offsets[d];
    int s1 = offsets[d + 1];

    float4 acc = make_float4(0.f, 0.f, 0.f, 0.f);
    auto addrow = [&](int r) {                    // r = src row index
        float dv = dinv[r];
        uint2 p = *(const uint2*)(gb + (r << 8));
        acc.x = fmaf(bflo(p.x), dv, acc.x);
        acc.y = fmaf(bfhi(p.x), dv, acc.y);
        acc.z = fmaf(bflo(p.y), dv, acc.z);
        acc.w = fmaf(bfhi(p.y), dv, acc.w);
    };

    addrow(d);  // self-loop: contributes dinv[d]*g[d]
    int e = s0;
    for (; e + 8 <= s1; e += 8) {
        int a[8];
        #pragma unroll
        for (int j = 0; j < 8; ++j) a[j] = sorted_src[e + j];
        #pragma unroll
        for (int j = 0; j < 8; ++j) addrow(a[j]);
    }
    for (; e + 4 <= s1; e += 4) {
        int a[4];
        #pragma unroll
        for (int j = 0; j < 4; ++j) a[j] = sorted_src[e + j];
        #pragma unroll
        for (int j = 0; j < 4; ++j) addrow(a[j]);
    }
    for (; e < s1; ++e) addrow(sorted_src[e]);

    float s = dinv[d];
    float4 bb = *(const float4*)(b + c);
    float4 r = make_float4(acc.x * s + bb.x, acc.y * s + bb.y,
                           acc.z * s + bb.z, acc.w * s + bb.w);
    *(float4*)(out + (long)d * 128 + c) = r;
}

// ============ launch ============

extern "C" void kernel_launch(void* const* d_in, const int* in_sizes, int n_in,
                              void* d_out, int out_size, void* d_ws, size_t ws_size,
                              hipStream_t stream) {
    const float* x  = (const float*)d_in[0];
    const int*   ei = (const int*)d_in[1];
    // d_in[2] = edge_attr (unused; GCN edge weight = 1)
    const float* W  = (const float*)d_in[3];
    const float* b  = (const float*)d_in[4];
    float* out = (float*)d_out;

    const int N = in_sizes[0] / 128;
    const int E = in_sizes[1] / 2;
    const int* src = ei;
    const int* dst = ei + E;
    const int NB = (N + 255) >> BSH;   // 391 buckets (<= 512)

    // ---- workspace carve (~40 MB) ----
    char* p = (char*)d_ws;
    auto carve = [&](size_t bytes) { char* q = p; p += (bytes + 255) & ~(size_t)255; return q; };
    int*            blockhist  = (int*)           carve((size_t)NBLK * 512 * 4);
    int*            ctot       = (int*)           carve(512 * 4);
    int*            offsets    = (int*)           carve((size_t)(N + 1) * 4);
    float*          dinv       = (float*)         carve((size_t)N * 4);
    unsigned*       packed     = (unsigned*)      carve((size_t)E * 4);
    int*            sorted_src = (int*)           carve((size_t)E * 4);
    unsigned short* wbf        = (unsigned short*)carve((size_t)128 * 128 * 2);
    unsigned short* g          = (unsigned short*)carve((size_t)N * 128 * 2);

    const int gemmBlocks = (N + 63) / 64;

    k_bhist   <<<NBLK, TPB, 0, stream>>>(dst, blockhist, W, wbf, E);
    k_bpfx    <<<128, TPB, 0, stream>>>(blockhist, ctot);
    k_bscatter<<<NBLK, TPB, 0, stream>>>(src, dst, blockhist, ctot, packed, E);
    k_csrgemm <<<NBLK + gemmBlocks, TPB, 0, stream>>>(packed, ctot, offsets, sorted_src,
                                                      dinv, x, wbf, g, N, E, NB);

    k_aggregate<<<(N + (TPB / 32) - 1) / (TPB / 32), TPB, 0, stream>>>(
        sorted_src, offsets, g, dinv, b, out, N);
}